// Round 9
// baseline (264.287 us; speedup 1.0000x reference)
//
#include <hip/hip_runtime.h>
#include <math.h>

#define B 128
#define M 32
#define P 8732
#define C 21
#define ALPHA 10.0f
#define NB2 35           // per-image partial count (kept for exact sum order)
#define NSUB 140         // 35*4 sub-tiles of 64 priors
#define CH 8             // k1 prior chunks (A0 pass replicates exactly)
#define CS 1092          // ceil(P / CH)

typedef float fx4 __attribute__((ext_vector_type(4)));
typedef fx4 fx4u __attribute__((aligned(4)));   // 4B-aligned vector load

#define CE1(val, idx) { float xv_ = (val); se += __expf(xv_); if (cls == (idx)) vc = xv_; }

// ---------------- k0: zero the done counter (workspace is poisoned) ---------
__global__ void k0_init(int* __restrict__ done) {
  if (threadIdx.x == 0) *done = 0;
}

// ---------------- phase A worker: KN subtiles, cls PRELOADED into regs ------
// All 3*21 cls values are loaded before the IoU m-loop so ~18 global loads
// are in flight under ~2000 VALU instructions (R8's 44-VGPR codegen did one
// prior at a time -> one L3 latency per prior = the 70us phase-A stall).
template <int KN>
__device__ __forceinline__ void phaseA_group(
    int b, int wid, int lane, int koff, int ntw,
    const float* __restrict__ pred_loc, const float* __restrict__ pred_cls,
    const float* __restrict__ priors,
    const float4* sbox, const int* slab, const int* sobj,
    float* s, float* psl, float* psc, int* psn) {
  float x1[KN], y1[KN], x2[KN], y2[KN], ap[KN];
  float bIr[KN], bUr[KN];
  int bmr[KN], fmr[KN];
  fx4 ca[KN], cb[KN], cc[KN], cd[KN], ce4[KN];
  float c20[KN];
#pragma unroll
  for (int j = 0; j < KN; j++) {
    int k = koff + j;
    int p = ((wid + (k << 4)) << 6) + lane;
    x1[j] = 0.0f; y1[j] = 0.0f; x2[j] = 0.0f; y2[j] = 0.0f; ap[j] = 0.0f;
    bIr[j] = -1.0f; bUr[j] = 1.0f; bmr[j] = 0; fmr[j] = 0x7fffffff;
    fx4 z = {0.0f, 0.0f, 0.0f, 0.0f};
    ca[j] = z; cb[j] = z; cc[j] = z; cd[j] = z; ce4[j] = z; c20[j] = 0.0f;
    if (k < ntw && p < P) {
      float4 pr = ((const float4*)priors)[p];
      float pw2 = pr.z * 0.5f, ph2 = pr.w * 0.5f;
      x1[j] = pr.x - pw2; y1[j] = pr.y - ph2;
      x2[j] = pr.x + pw2; y2[j] = pr.y + ph2;
      ap[j] = pr.z * pr.w;
      const float* uu = pred_cls + ((size_t)b * P + p) * C;
      const fx4u* u4 = (const fx4u*)uu;
      ca[j] = u4[0]; cb[j] = u4[1]; cc[j] = u4[2]; cd[j] = u4[3]; ce4[j] = u4[4];
      c20[j] = uu[20];
    }
  }
  // IoU: object loop outside (one LDS broadcast per object), covers the
  // in-flight cls loads above.
  for (int m = 0; m < M; m++) {
    float4 bx = sbox[m];
    float areaB = (bx.z - bx.x) * (bx.w - bx.y);
    int objm = sobj[m];
#pragma unroll
    for (int j = 0; j < KN; j++) {
      float iw = fminf(bx.z, x2[j]) - fmaxf(bx.x, x1[j]);
      float ih = fminf(bx.w, y2[j]) - fmaxf(bx.y, y1[j]);
      iw = fmaxf(iw, 0.0f);
      ih = fmaxf(ih, 0.0f);
      float inter = iw * ih;
      float uni = areaB + ap[j] - inter;
      if (inter * bUr[j] > bIr[j] * uni) { bIr[j] = inter; bUr[j] = uni; bmr[j] = m; }
      int p = ((wid + ((koff + j) << 4)) << 6) + lane;
      if (fmr[j] == 0x7fffffff && objm == p) fmr[j] = m;
    }
  }
#pragma unroll
  for (int j = 0; j < KN; j++) {
    int k = koff + j;
    if (k < ntw) {                     // wave-uniform guard
      int t = wid + (k << 4);
      int p = (t << 6) + lane;
      float locpart = 0.0f, cepospart = 0.0f;
      int npos = 0;
      if (p < P) {
        float bIv = bIr[j], bUv = bUr[j];
        int bmv = bmr[j], fmv = fmr[j];
        // forced best-prior override (first-max semantics preserved)
        if (fmv != 0x7fffffff) {
          if (!((bIv == bUv) && (bmv < fmv))) { bIv = 1.0f; bUv = 1.0f; bmv = fmv; }
        }
        bool pos = (2.0f * bIv >= bUv);  // iou >= 0.5, division-free
        int wAny = __any((int)pos);
        if (wAny) {                      // wave-uniform positive path (rare)
          float4 pr = ((const float4*)priors)[p];   // reload (cache-hot)
          float4 plv = ((const float4*)pred_loc)[(size_t)b * P + p];
          float4 bx = sbox[bmv];
          float cx = (bx.x + bx.z) * 0.5f, cy = (bx.y + bx.w) * 0.5f;
          float w = bx.z - bx.x, h = bx.w - bx.y;
          float rz = __builtin_amdgcn_rcpf(pr.z);
          float rw = __builtin_amdgcn_rcpf(pr.w);
          float g0 = (cx - pr.x) * 10.0f * rz;
          float g1 = (cy - pr.y) * 10.0f * rw;
          float g2 = __logf(w * rz) * 5.0f;
          float g3 = __logf(h * rw) * 5.0f;
          if (pos) {
            locpart = fabsf(plv.x - g0) + fabsf(plv.y - g1) +
                      fabsf(plv.z - g2) + fabsf(plv.w - g3);
            npos = 1;
          }
        }
        // CE from preloaded registers, exact c=0..20 chain
        int cls = pos ? slab[bmv] : 0;
        float se = 0.0f, vc = 0.0f;
        CE1(ca[j].x, 0)  CE1(ca[j].y, 1)  CE1(ca[j].z, 2)  CE1(ca[j].w, 3)
        CE1(cb[j].x, 4)  CE1(cb[j].y, 5)  CE1(cb[j].z, 6)  CE1(cb[j].w, 7)
        CE1(cc[j].x, 8)  CE1(cc[j].y, 9)  CE1(cc[j].z, 10) CE1(cc[j].w, 11)
        CE1(cd[j].x, 12) CE1(cd[j].y, 13) CE1(cd[j].z, 14) CE1(cd[j].w, 15)
        CE1(ce4[j].x, 16) CE1(ce4[j].y, 17) CE1(ce4[j].z, 18) CE1(ce4[j].w, 19)
        CE1(c20[j], 20)
        float ce = __logf(se) - vc;
        s[p] = pos ? 0.0f : ce;      // confneg stays in LDS
        cepospart = pos ? ce : 0.0f;
      }
      // wave reduce (same tree as before; all 64 lanes participate)
      for (int off = 32; off >= 1; off >>= 1) {
        locpart += __shfl_down(locpart, off, 64);
        cepospart += __shfl_down(cepospart, off, 64);
        npos += __shfl_down(npos, off, 64);
      }
      if (lane == 0) { psl[t] = locpart; psc[t] = cepospart; psn[t] = npos; }
    }
  }
}

// ---------------- k23: ONE BLOCK PER IMAGE — k1 + match + CE + radix --------
__global__ __launch_bounds__(1024) void k23_img(
    const float* __restrict__ pred_loc, const float* __restrict__ pred_cls,
    const float* __restrict__ b_boxes, const int* __restrict__ b_labels,
    const float* __restrict__ priors,
    float* __restrict__ imgres, int* __restrict__ done,
    float* __restrict__ out) {
  int b = blockIdx.x;
  int tid = threadIdx.x;
  int wid = tid >> 6;
  int lane = tid & 63;

  __shared__ __align__(16) float s[P];       // confneg row (never leaves LDS)
  __shared__ __align__(16) float4 sbox[M];
  __shared__ int slab[M], sobj[M];
  __shared__ float kIs[M][CH], kUs[M][CH];   // A0 chunk partials (k1 replica)
  __shared__ int kix[M][CH];
  __shared__ float psl[NSUB], psc[NSUB];     // per-64-prior-subtile partials
  __shared__ int psn[NSUB];
  __shared__ int histw[16 * 256];
  __shared__ __align__(16) int cnt[256];
  __shared__ int sdig, scum, sK, sLast;
  __shared__ float sLoc, sCe, sNp;
  __shared__ float rsum[16], rl[16], rc[16], rh[16], rn[16];
  __shared__ int rcnt[16];

  if (tid < M) {
    int m = tid;
    float4 bx = ((const float4*)b_boxes)[b * M + m];
    sbox[m] = bx;
    slab[m] = b_labels[b * M + m];
  }
  __syncthreads();

  // ---------- A0: best prior per object — exact k1 replica, 2 jobs/wave -----
  for (int q = wid; q < 32; q += 16) {
    int g = q >> 3;
    int ch = q & 7;
    int obase = g * 8;
    float ox1[8], oy1[8], ox2[8], oy2[8], oarea[8], bI[8], bU[8];
    int bidx[8];
#pragma unroll
    for (int k = 0; k < 8; k++) {
      float4 bx = sbox[obase + k];     // same bits as k1's global read
      ox1[k] = bx.x; oy1[k] = bx.y; ox2[k] = bx.z; oy2[k] = bx.w;
      oarea[k] = (bx.z - bx.x) * (bx.w - bx.y);
      bI[k] = -1.0f; bU[k] = 1.0f; bidx[k] = P;
    }
    int pend = (ch + 1) * CS;
    if (pend > P) pend = P;
#pragma unroll 2
    for (int p = ch * CS + lane; p < pend; p += 64) {
      float4 pr = ((const float4*)priors)[p];
      float pw2 = pr.z * 0.5f, ph2 = pr.w * 0.5f;
      float px1 = pr.x - pw2, py1 = pr.y - ph2;
      float px2 = pr.x + pw2, py2 = pr.y + ph2;
      float areaP = pr.z * pr.w;
#pragma unroll
      for (int k = 0; k < 8; k++) {
        float iw = fminf(ox2[k], px2) - fmaxf(ox1[k], px1);
        float ih = fminf(oy2[k], py2) - fmaxf(oy1[k], py1);
        iw = fmaxf(iw, 0.0f);
        ih = fmaxf(ih, 0.0f);
        float inter = iw * ih;
        float uni = oarea[k] + areaP - inter;
        if (inter * bU[k] > bI[k] * uni) { bI[k] = inter; bU[k] = uni; bidx[k] = p; }
      }
    }
    for (int off = 32; off >= 1; off >>= 1) {
#pragma unroll
      for (int k = 0; k < 8; k++) {
        float oI = __shfl_xor(bI[k], off, 64);
        float oU = __shfl_xor(bU[k], off, 64);
        int oi = __shfl_xor(bidx[k], off, 64);
        float l = oI * bU[k], r = bI[k] * oU;
        if (l > r || (l == r && oi < bidx[k])) { bI[k] = oI; bU[k] = oU; bidx[k] = oi; }
      }
    }
    if (lane == 0) {
#pragma unroll
      for (int k = 0; k < 8; k++) {
        kIs[obase + k][ch] = bI[k]; kUs[obase + k][ch] = bU[k];
        kix[obase + k][ch] = bidx[k];
      }
    }
  }
  __syncthreads();
  if (tid < M) {   // exact k1_reduce fold, ch = 0..7
    int m = tid;
    float cI = kIs[m][0], cU = kUs[m][0];
    int ci = kix[m][0];
#pragma unroll
    for (int ch = 1; ch < CH; ch++) {
      float nI = kIs[m][ch], nU = kUs[m][ch];
      int ni = kix[m][ch];
      if (nI * cU > cI * nU) { cI = nI; cU = nU; ci = ni; }
    }
    sobj[m] = ci;
  }
  __syncthreads();

  // ---------- phase A: 140 sub-tiles over 16 waves, 3 groups of KN=3 --------
  int ntw = (wid < 12) ? 9 : 8;    // sub-tiles per wave (t = wid + k*16 < 140)
  phaseA_group<3>(b, wid, lane, 0, ntw, pred_loc, pred_cls, priors,
                  sbox, slab, sobj, s, psl, psc, psn);
  phaseA_group<3>(b, wid, lane, 3, ntw, pred_loc, pred_cls, priors,
                  sbox, slab, sobj, s, psl, psc, psn);
  phaseA_group<3>(b, wid, lane, 6, ntw, pred_loc, pred_cls, priors,
                  sbox, slab, sobj, s, psl, psc, psn);
  __syncthreads();

  // ---------- per-image partial reduce (old order: 4-subtile chain + tree) --
  if (wid == 0) {
    float lp = 0.0f, cp = 0.0f;
    int np = 0;
    if (lane < NB2) {
      int t4 = lane * 4;
      lp = ((psl[t4] + psl[t4 + 1]) + psl[t4 + 2]) + psl[t4 + 3];
      cp = ((psc[t4] + psc[t4 + 1]) + psc[t4 + 2]) + psc[t4 + 3];
      np = psn[t4] + psn[t4 + 1] + psn[t4 + 2] + psn[t4 + 3];
    }
    for (int off = 32; off >= 1; off >>= 1) {
      lp += __shfl_down(lp, off, 64);
      cp += __shfl_down(cp, off, 64);
      np += __shfl_down(np, off, 64);
    }
    if (lane == 0) {
      int K = np * 3;
      if (K > P) K = P;
      sK = K; sLoc = lp; sCe = cp; sNp = (float)np;
    }
  }
  __syncthreads();

  // ---------- radix top-K over LDS s[] (unchanged) --------------------------
  int K = sK;
  unsigned pfx = 0;
  int Krem = K;
#pragma unroll
  for (int pass = 3; pass >= 0; --pass) {
    int sh = pass * 8;
    for (int i = tid; i < 16 * 256; i += 1024) histw[i] = 0;
    __syncthreads();
    unsigned himask = (pass == 3) ? 0u : (0xFFFFFFFFu << (sh + 8));
    int* myh = &histw[wid * 256];
    for (int i = tid; i < P; i += 1024) {
      unsigned ub = __float_as_uint(s[i]);
      if ((ub & himask) == pfx) atomicAdd(&myh[(ub >> sh) & 255], 1);
    }
    __syncthreads();
    if (tid < 256) {
      int c = 0;
#pragma unroll
      for (int w = 0; w < 16; w++) c += histw[w * 256 + tid];
      cnt[tid] = c;
    }
    __syncthreads();
    if (wid == 0) {
      int4 c4 = ((const int4*)cnt)[lane];
      int s3 = c4.w;
      int s2 = c4.z + s3;
      int s1 = c4.y + s2;
      int s0 = c4.x + s1;
      int suf = s0;
      for (int off = 1; off < 64; off <<= 1) {
        int t = __shfl_down(suf, off, 64);
        if (lane + off < 64) suf += t;
      }
      int above = suf - s0;
      int S0 = above + s0, S1 = above + s1, S2 = above + s2, S3 = above + s3;
      int S4 = above;
      if (S3 >= Krem && S4 < Krem) { sdig = 4 * lane + 3; scum = S4; }
      else if (S2 >= Krem && S3 < Krem) { sdig = 4 * lane + 2; scum = S3; }
      else if (S1 >= Krem && S2 < Krem) { sdig = 4 * lane + 1; scum = S2; }
      else if (S0 >= Krem && S1 < Krem) { sdig = 4 * lane + 0; scum = S1; }
    }
    __syncthreads();
    pfx |= ((unsigned)sdig) << sh;
    Krem -= scum;
  }
  float tau = __uint_as_float(pfx);

  float sum = 0.0f;
  int cgt = 0;
  for (int i = tid; i < P; i += 1024) {
    float v = s[i];
    if (v > tau) { sum += v; cgt++; }
  }
  for (int off = 32; off >= 1; off >>= 1) {
    sum += __shfl_down(sum, off, 64);
    cgt += __shfl_down(cgt, off, 64);
  }
  if (lane == 0) { rsum[wid] = sum; rcnt[wid] = cgt; }
  __syncthreads();
  if (tid == 0) {
    float stot = 0.0f;
    int ctot = 0;
#pragma unroll
    for (int w = 0; w < 16; w++) { stot += rsum[w]; ctot += rcnt[w]; }
    float hard = stot + (float)(K - ctot) * tau;
    imgres[b * 4 + 0] = sLoc;
    imgres[b * 4 + 1] = sCe;
    imgres[b * 4 + 2] = hard;
    imgres[b * 4 + 3] = sNp;
    __threadfence();
    int prev = atomicAdd(done, 1);
    sLast = (prev == B - 1) ? 1 : 0;
  }
  __syncthreads();
  if (sLast) {
    __threadfence();
    float l = 0.0f, c = 0.0f, h = 0.0f, n = 0.0f;
    if (tid < B) {
      l = atomicAdd(&imgres[tid * 4 + 0], 0.0f);
      c = atomicAdd(&imgres[tid * 4 + 1], 0.0f);
      h = atomicAdd(&imgres[tid * 4 + 2], 0.0f);
      n = atomicAdd(&imgres[tid * 4 + 3], 0.0f);
    }
    for (int off = 32; off >= 1; off >>= 1) {
      l += __shfl_down(l, off, 64);
      c += __shfl_down(c, off, 64);
      h += __shfl_down(h, off, 64);
      n += __shfl_down(n, off, 64);
    }
    if (lane == 0) { rl[wid] = l; rc[wid] = c; rh[wid] = h; rn[wid] = n; }
    __syncthreads();
    if (tid == 0) {
      float L = 0, Cc = 0, H = 0, N = 0;
#pragma unroll
      for (int w = 0; w < 16; w++) { L += rl[w]; Cc += rc[w]; H += rh[w]; N += rn[w]; }
      float loc = ALPHA * L / (N * 4.0f);
      float conf = (H + Cc) / N;
      out[0] = conf + loc;
      out[1] = loc;
      out[2] = conf;
    }
  }
}

extern "C" void kernel_launch(void* const* d_in, const int* in_sizes, int n_in,
                              void* d_out, int out_size, void* d_ws, size_t ws_size,
                              hipStream_t stream) {
  (void)in_sizes; (void)n_in; (void)out_size; (void)ws_size;
  const float* pred_loc = (const float*)d_in[0];
  const float* pred_cls = (const float*)d_in[1];
  const float* b_boxes = (const float*)d_in[2];
  const int* b_labels = (const int*)d_in[3];
  const float* priors = (const float*)d_in[4];
  float* out = (float*)d_out;

  int* done = (int*)d_ws;
  float* imgres = (float*)d_ws + 8;

  k0_init<<<1, 64, 0, stream>>>(done);
  k23_img<<<B, 1024, 0, stream>>>(pred_loc, pred_cls, b_boxes, b_labels,
                                  priors, imgres, done, out);
}

// Round 10
// 262.053 us; speedup vs baseline: 1.0085x; 1.0085x over previous
//
#include <hip/hip_runtime.h>
#include <math.h>

#define B 128
#define M 32
#define P 8732
#define C 21
#define ALPHA 10.0f
#define NB2 35           // per-image partial count (kept for exact sum order)
#define NSUB 140         // 35*4 sub-tiles of 64 priors
#define CH 8             // k1 prior chunks (A0 pass replicates exactly)
#define CS 1092          // ceil(P / CH)

typedef float fx4 __attribute__((ext_vector_type(4)));
typedef fx4 fx4u __attribute__((aligned(4)));   // 4B-aligned vector load

#define CE1(val, idx) { float xv_ = (val); se += __expf(xv_); if (cls == (idx)) vc = xv_; }

// ---------------- k0: zero the done counter (workspace is poisoned) ---------
__global__ void k0_init(int* __restrict__ done) {
  if (threadIdx.x == 0) *done = 0;
}

// ---------------- phase A worker: KN subtiles, cls PRELOADED into regs ------
// All 3*21 cls values are loaded before the IoU m-loop so ~18 global loads
// are in flight under ~2000 VALU instructions. R9 lesson: this needs the
// 128-VGPR cap (launch_bounds min-waves/EU=4); at the compiler's default 64
// the arrays went to scratch and the kernel REGRESSED 85->150us.
template <int KN>
__device__ __forceinline__ void phaseA_group(
    int b, int wid, int lane, int koff, int ntw,
    const float* __restrict__ pred_loc, const float* __restrict__ pred_cls,
    const float* __restrict__ priors,
    const float4* sbox, const int* slab, const int* sobj,
    float* s, float* psl, float* psc, int* psn) {
  float x1[KN], y1[KN], x2[KN], y2[KN], ap[KN];
  float bIr[KN], bUr[KN];
  int bmr[KN], fmr[KN];
  fx4 ca[KN], cb[KN], cc[KN], cd[KN], ce4[KN];
  float c20[KN];
#pragma unroll
  for (int j = 0; j < KN; j++) {
    int k = koff + j;
    int p = ((wid + (k << 4)) << 6) + lane;
    x1[j] = 0.0f; y1[j] = 0.0f; x2[j] = 0.0f; y2[j] = 0.0f; ap[j] = 0.0f;
    bIr[j] = -1.0f; bUr[j] = 1.0f; bmr[j] = 0; fmr[j] = 0x7fffffff;
    fx4 z = {0.0f, 0.0f, 0.0f, 0.0f};
    ca[j] = z; cb[j] = z; cc[j] = z; cd[j] = z; ce4[j] = z; c20[j] = 0.0f;
    if (k < ntw && p < P) {
      float4 pr = ((const float4*)priors)[p];
      float pw2 = pr.z * 0.5f, ph2 = pr.w * 0.5f;
      x1[j] = pr.x - pw2; y1[j] = pr.y - ph2;
      x2[j] = pr.x + pw2; y2[j] = pr.y + ph2;
      ap[j] = pr.z * pr.w;
      const float* uu = pred_cls + ((size_t)b * P + p) * C;
      const fx4u* u4 = (const fx4u*)uu;
      ca[j] = u4[0]; cb[j] = u4[1]; cc[j] = u4[2]; cd[j] = u4[3]; ce4[j] = u4[4];
      c20[j] = uu[20];
    }
  }
  // IoU: object loop outside (one LDS broadcast per object), covers the
  // in-flight cls loads above.
  for (int m = 0; m < M; m++) {
    float4 bx = sbox[m];
    float areaB = (bx.z - bx.x) * (bx.w - bx.y);
    int objm = sobj[m];
#pragma unroll
    for (int j = 0; j < KN; j++) {
      float iw = fminf(bx.z, x2[j]) - fmaxf(bx.x, x1[j]);
      float ih = fminf(bx.w, y2[j]) - fmaxf(bx.y, y1[j]);
      iw = fmaxf(iw, 0.0f);
      ih = fmaxf(ih, 0.0f);
      float inter = iw * ih;
      float uni = areaB + ap[j] - inter;
      if (inter * bUr[j] > bIr[j] * uni) { bIr[j] = inter; bUr[j] = uni; bmr[j] = m; }
      int p = ((wid + ((koff + j) << 4)) << 6) + lane;
      if (fmr[j] == 0x7fffffff && objm == p) fmr[j] = m;
    }
  }
#pragma unroll
  for (int j = 0; j < KN; j++) {
    int k = koff + j;
    if (k < ntw) {                     // wave-uniform guard
      int t = wid + (k << 4);
      int p = (t << 6) + lane;
      float locpart = 0.0f, cepospart = 0.0f;
      int npos = 0;
      if (p < P) {
        float bIv = bIr[j], bUv = bUr[j];
        int bmv = bmr[j], fmv = fmr[j];
        // forced best-prior override (first-max semantics preserved)
        if (fmv != 0x7fffffff) {
          if (!((bIv == bUv) && (bmv < fmv))) { bIv = 1.0f; bUv = 1.0f; bmv = fmv; }
        }
        bool pos = (2.0f * bIv >= bUv);  // iou >= 0.5, division-free
        int wAny = __any((int)pos);
        if (wAny) {                      // wave-uniform positive path (rare)
          float4 pr = ((const float4*)priors)[p];   // reload (cache-hot)
          float4 plv = ((const float4*)pred_loc)[(size_t)b * P + p];
          float4 bx = sbox[bmv];
          float cx = (bx.x + bx.z) * 0.5f, cy = (bx.y + bx.w) * 0.5f;
          float w = bx.z - bx.x, h = bx.w - bx.y;
          float rz = __builtin_amdgcn_rcpf(pr.z);
          float rw = __builtin_amdgcn_rcpf(pr.w);
          float g0 = (cx - pr.x) * 10.0f * rz;
          float g1 = (cy - pr.y) * 10.0f * rw;
          float g2 = __logf(w * rz) * 5.0f;
          float g3 = __logf(h * rw) * 5.0f;
          if (pos) {
            locpart = fabsf(plv.x - g0) + fabsf(plv.y - g1) +
                      fabsf(plv.z - g2) + fabsf(plv.w - g3);
            npos = 1;
          }
        }
        // CE from preloaded registers, exact c=0..20 chain
        int cls = pos ? slab[bmv] : 0;
        float se = 0.0f, vc = 0.0f;
        CE1(ca[j].x, 0)  CE1(ca[j].y, 1)  CE1(ca[j].z, 2)  CE1(ca[j].w, 3)
        CE1(cb[j].x, 4)  CE1(cb[j].y, 5)  CE1(cb[j].z, 6)  CE1(cb[j].w, 7)
        CE1(cc[j].x, 8)  CE1(cc[j].y, 9)  CE1(cc[j].z, 10) CE1(cc[j].w, 11)
        CE1(cd[j].x, 12) CE1(cd[j].y, 13) CE1(cd[j].z, 14) CE1(cd[j].w, 15)
        CE1(ce4[j].x, 16) CE1(ce4[j].y, 17) CE1(ce4[j].z, 18) CE1(ce4[j].w, 19)
        CE1(c20[j], 20)
        float ce = __logf(se) - vc;
        s[p] = pos ? 0.0f : ce;      // confneg stays in LDS
        cepospart = pos ? ce : 0.0f;
      }
      // wave reduce (same tree as before; all 64 lanes participate)
      for (int off = 32; off >= 1; off >>= 1) {
        locpart += __shfl_down(locpart, off, 64);
        cepospart += __shfl_down(cepospart, off, 64);
        npos += __shfl_down(npos, off, 64);
      }
      if (lane == 0) { psl[t] = locpart; psc[t] = cepospart; psn[t] = npos; }
    }
  }
}

// ---------------- k23: ONE BLOCK PER IMAGE — k1 + match + CE + radix --------
// launch_bounds(1024, 4): grid is 128 blocks on 256 CUs, so only 1 block/CU
// is ever resident; min-4-waves/EU raises the VGPR cap to 128 so the phase-A
// preload stays in registers (R9: default cap 64 -> scratch -> 150us).
__global__ __launch_bounds__(1024, 4) void k23_img(
    const float* __restrict__ pred_loc, const float* __restrict__ pred_cls,
    const float* __restrict__ b_boxes, const int* __restrict__ b_labels,
    const float* __restrict__ priors,
    float* __restrict__ imgres, int* __restrict__ done,
    float* __restrict__ out) {
  int b = blockIdx.x;
  int tid = threadIdx.x;
  int wid = tid >> 6;
  int lane = tid & 63;

  __shared__ __align__(16) float s[P];       // confneg row (never leaves LDS)
  __shared__ __align__(16) float4 sbox[M];
  __shared__ int slab[M], sobj[M];
  __shared__ float kIs[M][CH], kUs[M][CH];   // A0 chunk partials (k1 replica)
  __shared__ int kix[M][CH];
  __shared__ float psl[NSUB], psc[NSUB];     // per-64-prior-subtile partials
  __shared__ int psn[NSUB];
  __shared__ int histw[16 * 256];
  __shared__ __align__(16) int cnt[256];
  __shared__ int sdig, scum, sK, sLast;
  __shared__ float sLoc, sCe, sNp;
  __shared__ float rsum[16], rl[16], rc[16], rh[16], rn[16];
  __shared__ int rcnt[16];

  if (tid < M) {
    int m = tid;
    float4 bx = ((const float4*)b_boxes)[b * M + m];
    sbox[m] = bx;
    slab[m] = b_labels[b * M + m];
  }
  __syncthreads();

  // ---------- A0: best prior per object — exact k1 replica, 2 jobs/wave -----
  for (int q = wid; q < 32; q += 16) {
    int g = q >> 3;
    int ch = q & 7;
    int obase = g * 8;
    float ox1[8], oy1[8], ox2[8], oy2[8], oarea[8], bI[8], bU[8];
    int bidx[8];
#pragma unroll
    for (int k = 0; k < 8; k++) {
      float4 bx = sbox[obase + k];     // same bits as k1's global read
      ox1[k] = bx.x; oy1[k] = bx.y; ox2[k] = bx.z; oy2[k] = bx.w;
      oarea[k] = (bx.z - bx.x) * (bx.w - bx.y);
      bI[k] = -1.0f; bU[k] = 1.0f; bidx[k] = P;
    }
    int pend = (ch + 1) * CS;
    if (pend > P) pend = P;
#pragma unroll 2
    for (int p = ch * CS + lane; p < pend; p += 64) {
      float4 pr = ((const float4*)priors)[p];
      float pw2 = pr.z * 0.5f, ph2 = pr.w * 0.5f;
      float px1 = pr.x - pw2, py1 = pr.y - ph2;
      float px2 = pr.x + pw2, py2 = pr.y + ph2;
      float areaP = pr.z * pr.w;
#pragma unroll
      for (int k = 0; k < 8; k++) {
        float iw = fminf(ox2[k], px2) - fmaxf(ox1[k], px1);
        float ih = fminf(oy2[k], py2) - fmaxf(oy1[k], py1);
        iw = fmaxf(iw, 0.0f);
        ih = fmaxf(ih, 0.0f);
        float inter = iw * ih;
        float uni = oarea[k] + areaP - inter;
        if (inter * bU[k] > bI[k] * uni) { bI[k] = inter; bU[k] = uni; bidx[k] = p; }
      }
    }
    for (int off = 32; off >= 1; off >>= 1) {
#pragma unroll
      for (int k = 0; k < 8; k++) {
        float oI = __shfl_xor(bI[k], off, 64);
        float oU = __shfl_xor(bU[k], off, 64);
        int oi = __shfl_xor(bidx[k], off, 64);
        float l = oI * bU[k], r = bI[k] * oU;
        if (l > r || (l == r && oi < bidx[k])) { bI[k] = oI; bU[k] = oU; bidx[k] = oi; }
      }
    }
    if (lane == 0) {
#pragma unroll
      for (int k = 0; k < 8; k++) {
        kIs[obase + k][ch] = bI[k]; kUs[obase + k][ch] = bU[k];
        kix[obase + k][ch] = bidx[k];
      }
    }
  }
  __syncthreads();
  if (tid < M) {   // exact k1_reduce fold, ch = 0..7
    int m = tid;
    float cI = kIs[m][0], cU = kUs[m][0];
    int ci = kix[m][0];
#pragma unroll
    for (int ch = 1; ch < CH; ch++) {
      float nI = kIs[m][ch], nU = kUs[m][ch];
      int ni = kix[m][ch];
      if (nI * cU > cI * nU) { cI = nI; cU = nU; ci = ni; }
    }
    sobj[m] = ci;
  }
  __syncthreads();

  // ---------- phase A: 140 sub-tiles over 16 waves, 3 groups of KN=3 --------
  int ntw = (wid < 12) ? 9 : 8;    // sub-tiles per wave (t = wid + k*16 < 140)
  phaseA_group<3>(b, wid, lane, 0, ntw, pred_loc, pred_cls, priors,
                  sbox, slab, sobj, s, psl, psc, psn);
  phaseA_group<3>(b, wid, lane, 3, ntw, pred_loc, pred_cls, priors,
                  sbox, slab, sobj, s, psl, psc, psn);
  phaseA_group<3>(b, wid, lane, 6, ntw, pred_loc, pred_cls, priors,
                  sbox, slab, sobj, s, psl, psc, psn);
  __syncthreads();

  // ---------- per-image partial reduce (old order: 4-subtile chain + tree) --
  if (wid == 0) {
    float lp = 0.0f, cp = 0.0f;
    int np = 0;
    if (lane < NB2) {
      int t4 = lane * 4;
      lp = ((psl[t4] + psl[t4 + 1]) + psl[t4 + 2]) + psl[t4 + 3];
      cp = ((psc[t4] + psc[t4 + 1]) + psc[t4 + 2]) + psc[t4 + 3];
      np = psn[t4] + psn[t4 + 1] + psn[t4 + 2] + psn[t4 + 3];
    }
    for (int off = 32; off >= 1; off >>= 1) {
      lp += __shfl_down(lp, off, 64);
      cp += __shfl_down(cp, off, 64);
      np += __shfl_down(np, off, 64);
    }
    if (lane == 0) {
      int K = np * 3;
      if (K > P) K = P;
      sK = K; sLoc = lp; sCe = cp; sNp = (float)np;
    }
  }
  __syncthreads();

  // ---------- radix top-K over LDS s[] (unchanged) --------------------------
  int K = sK;
  unsigned pfx = 0;
  int Krem = K;
#pragma unroll
  for (int pass = 3; pass >= 0; --pass) {
    int sh = pass * 8;
    for (int i = tid; i < 16 * 256; i += 1024) histw[i] = 0;
    __syncthreads();
    unsigned himask = (pass == 3) ? 0u : (0xFFFFFFFFu << (sh + 8));
    int* myh = &histw[wid * 256];
    for (int i = tid; i < P; i += 1024) {
      unsigned ub = __float_as_uint(s[i]);
      if ((ub & himask) == pfx) atomicAdd(&myh[(ub >> sh) & 255], 1);
    }
    __syncthreads();
    if (tid < 256) {
      int c = 0;
#pragma unroll
      for (int w = 0; w < 16; w++) c += histw[w * 256 + tid];
      cnt[tid] = c;
    }
    __syncthreads();
    if (wid == 0) {
      int4 c4 = ((const int4*)cnt)[lane];
      int s3 = c4.w;
      int s2 = c4.z + s3;
      int s1 = c4.y + s2;
      int s0 = c4.x + s1;
      int suf = s0;
      for (int off = 1; off < 64; off <<= 1) {
        int t = __shfl_down(suf, off, 64);
        if (lane + off < 64) suf += t;
      }
      int above = suf - s0;
      int S0 = above + s0, S1 = above + s1, S2 = above + s2, S3 = above + s3;
      int S4 = above;
      if (S3 >= Krem && S4 < Krem) { sdig = 4 * lane + 3; scum = S4; }
      else if (S2 >= Krem && S3 < Krem) { sdig = 4 * lane + 2; scum = S3; }
      else if (S1 >= Krem && S2 < Krem) { sdig = 4 * lane + 1; scum = S2; }
      else if (S0 >= Krem && S1 < Krem) { sdig = 4 * lane + 0; scum = S1; }
    }
    __syncthreads();
    pfx |= ((unsigned)sdig) << sh;
    Krem -= scum;
  }
  float tau = __uint_as_float(pfx);

  float sum = 0.0f;
  int cgt = 0;
  for (int i = tid; i < P; i += 1024) {
    float v = s[i];
    if (v > tau) { sum += v; cgt++; }
  }
  for (int off = 32; off >= 1; off >>= 1) {
    sum += __shfl_down(sum, off, 64);
    cgt += __shfl_down(cgt, off, 64);
  }
  if (lane == 0) { rsum[wid] = sum; rcnt[wid] = cgt; }
  __syncthreads();
  if (tid == 0) {
    float stot = 0.0f;
    int ctot = 0;
#pragma unroll
    for (int w = 0; w < 16; w++) { stot += rsum[w]; ctot += rcnt[w]; }
    float hard = stot + (float)(K - ctot) * tau;
    imgres[b * 4 + 0] = sLoc;
    imgres[b * 4 + 1] = sCe;
    imgres[b * 4 + 2] = hard;
    imgres[b * 4 + 3] = sNp;
    __threadfence();
    int prev = atomicAdd(done, 1);
    sLast = (prev == B - 1) ? 1 : 0;
  }
  __syncthreads();
  if (sLast) {
    __threadfence();
    float l = 0.0f, c = 0.0f, h = 0.0f, n = 0.0f;
    if (tid < B) {
      l = atomicAdd(&imgres[tid * 4 + 0], 0.0f);
      c = atomicAdd(&imgres[tid * 4 + 1], 0.0f);
      h = atomicAdd(&imgres[tid * 4 + 2], 0.0f);
      n = atomicAdd(&imgres[tid * 4 + 3], 0.0f);
    }
    for (int off = 32; off >= 1; off >>= 1) {
      l += __shfl_down(l, off, 64);
      c += __shfl_down(c, off, 64);
      h += __shfl_down(h, off, 64);
      n += __shfl_down(n, off, 64);
    }
    if (lane == 0) { rl[wid] = l; rc[wid] = c; rh[wid] = h; rn[wid] = n; }
    __syncthreads();
    if (tid == 0) {
      float L = 0, Cc = 0, H = 0, N = 0;
#pragma unroll
      for (int w = 0; w < 16; w++) { L += rl[w]; Cc += rc[w]; H += rh[w]; N += rn[w]; }
      float loc = ALPHA * L / (N * 4.0f);
      float conf = (H + Cc) / N;
      out[0] = conf + loc;
      out[1] = loc;
      out[2] = conf;
    }
  }
}

extern "C" void kernel_launch(void* const* d_in, const int* in_sizes, int n_in,
                              void* d_out, int out_size, void* d_ws, size_t ws_size,
                              hipStream_t stream) {
  (void)in_sizes; (void)n_in; (void)out_size; (void)ws_size;
  const float* pred_loc = (const float*)d_in[0];
  const float* pred_cls = (const float*)d_in[1];
  const float* b_boxes = (const float*)d_in[2];
  const int* b_labels = (const int*)d_in[3];
  const float* priors = (const float*)d_in[4];
  float* out = (float*)d_out;

  int* done = (int*)d_ws;
  float* imgres = (float*)d_ws + 8;

  k0_init<<<1, 64, 0, stream>>>(done);
  k23_img<<<B, 1024, 0, stream>>>(pred_loc, pred_cls, b_boxes, b_labels,
                                  priors, imgres, done, out);
}